// Round 4
// baseline (115.489 us; speedup 1.0000x reference)
//
#include <hip/hip_runtime.h>
#include <hip/hip_bf16.h>

typedef float f32x4 __attribute__((ext_vector_type(4)));
typedef short s16x8 __attribute__((ext_vector_type(8)));

#define LOG2_N 2.887525271f   // log2(7.4)
#define HALF_N 3.7f           // n_param / 2

// ---------------- kernel 1: A[m,k] = 3.7 * clip(x,0,1)^log2(7.4)  (bf16) ----
__global__ __launch_bounds__(256) void fv_kernel(const float* __restrict__ x,
                                                 __hip_bfloat16* __restrict__ a,
                                                 int total4) {
  int i = blockIdx.x * blockDim.x + threadIdx.x;
  if (i >= total4) return;
  float4 v = reinterpret_cast<const float4*>(x)[i];
  const float* vp = reinterpret_cast<const float*>(&v);
  union { ushort4 u4; ushort s[4]; } o;
#pragma unroll
  for (int j = 0; j < 4; ++j) {
    float xc = fminf(fmaxf(vp[j], 0.0f), 1.0f);
    float r = (xc > 0.0f) ? HALF_N * exp2f(LOG2_N * __log2f(xc)) : 0.0f;
    __hip_bfloat16 h = __float2bfloat16(r);
    o.s[j] = *reinterpret_cast<ushort*>(&h);
  }
  reinterpret_cast<ushort4*>(a)[i] = o.u4;
}

// ---------------- kernel 2: WT[n][k] = bf16(w[k][n]) ------------------------
__global__ __launch_bounds__(256) void wt_kernel(const float* __restrict__ w,
                                                 __hip_bfloat16* __restrict__ wt,
                                                 int K, int N) {
  __shared__ float tile[64][65];
  const int n0 = blockIdx.x * 64;
  const int k0 = blockIdx.y * 64;
  const int tid = threadIdx.x;
#pragma unroll
  for (int i = 0; i < 16; ++i) {
    const int lin = i * 256 + tid;
    const int r = lin >> 6;   // k within tile
    const int c = lin & 63;   // n within tile
    tile[r][c] = w[(size_t)(k0 + r) * N + (n0 + c)];
  }
  __syncthreads();
  const int kk = (tid & 31) * 2;  // 0..62, even
  const int r0 = tid >> 5;        // 0..7
#pragma unroll
  for (int i = 0; i < 8; ++i) {
    const int r = r0 + i * 8;     // n within tile
    __hip_bfloat16 h0 = __float2bfloat16(tile[kk][r]);
    __hip_bfloat16 h1 = __float2bfloat16(tile[kk + 1][r]);
    ushort2 u;
    u.x = *reinterpret_cast<ushort*>(&h0);
    u.y = *reinterpret_cast<ushort*>(&h1);
    *reinterpret_cast<ushort2*>(&wt[(size_t)(n0 + r) * K + (k0 + kk)]) = u;
  }
}

// -- kernel 3: 4-wave 128x256 GEMM, wave tile 128x64, reg-pipelined kk-halves -
#define BM 128
#define BN 256
#define BK 64
#define LDS_HALF 24576   // ushorts per buffer (48 KB): A[128][64] + B[256][64]
#define B_OFF 8192

#define GLD16(g, l)                                              \
  __builtin_amdgcn_global_load_lds(                              \
      (const __attribute__((address_space(1))) void*)(g),        \
      (__attribute__((address_space(3))) void*)(l), 16, 0, 0)

__global__ __launch_bounds__(256, 1) void gemm_kernel(
    const __hip_bfloat16* __restrict__ A,   // [M][K] bf16
    const __hip_bfloat16* __restrict__ BT,  // [N][K] bf16
    const float* __restrict__ bias,         // [N]
    float* __restrict__ C,                  // [M][N]
    int M, int N, int K) {
  __shared__ ushort lds[3 * LDS_HALF];   // 144 KB, 3-deep circular

  const int NTM = M / BM;               // 16
  const int NTN = N / BN;               // 16
  const int nwg = NTM * NTN;            // 256

  // XCD-aware bijective swizzle (nwg % 8 == 0)
  int wg = (int)blockIdx.x;
  if ((nwg & 7) == 0) wg = (wg & 7) * (nwg >> 3) + (wg >> 3);
  const int nt = wg / NTM;              // B-panel resident per XCD
  const int mt = wg % NTM;
  const int m0 = mt * BM;
  const int n0 = nt * BN;

  const int tid = threadIdx.x;
  const int lane = tid & 63;
  const int wid = tid >> 6;   // 0..3; wave owns rows 0..127, cols wid*64..+63

  const ushort* Au = (const ushort*)A;
  const ushort* Bu = (const ushort*)BT;

  // ---- staging (pre-swizzled global source, linear LDS dest) ----
  // LDS[row][c16] holds global[row][c16 ^ (row&7)]
  const int l8 = lane >> 3;
  const int c16s = (lane & 7) ^ l8;
  // A: wave stages rows [wid*32, wid*32+32) as 4 chunks of 8 rows
  const ushort* aSrc = Au + (size_t)(m0 + wid * 32 + l8) * K + c16s * 8;
  // B: wave stages rows [wid*64, wid*64+64) as 8 chunks
  const ushort* bSrc = Bu + (size_t)(n0 + wid * 64 + l8) * K + c16s * 8;
  const int aDst = (wid * 32) * 64;           // ushort offset
  const int bDst = B_OFF + (wid * 64) * 64;

  auto stage = [&](ushort* ldsb, int t) {     // 12 gld_lds = 12 KB/wave
    const size_t to = (size_t)t * BK;
#pragma unroll
    for (int c = 0; c < 4; ++c)
      GLD16(aSrc + to + (size_t)(c * 8) * K, ldsb + aDst + c * 512);
#pragma unroll
    for (int c = 0; c < 8; ++c)
      GLD16(bSrc + to + (size_t)(c * 8) * K, ldsb + bDst + c * 512);
  };

  // ---- fragment read addressing (swizzled ds_read) ----
  const int frow = lane & 15;
  const int lhi = lane >> 4;                 // 0..3
  const int f7 = frow & 7;
  const int bRowB = B_OFF + (wid * 64 + frow) * 64;

  auto loadFrags = [&](s16x8 (&a)[8], s16x8 (&b)[4], const ushort* ldsb, int kk) {
    const int sck = ((kk * 4 + lhi) ^ f7) * 8;
#pragma unroll
    for (int mi = 0; mi < 8; ++mi)
      a[mi] = *(const s16x8*)&ldsb[(mi * 16 + frow) * 64 + sck];
#pragma unroll
    for (int ni = 0; ni < 4; ++ni)
      b[ni] = *(const s16x8*)&ldsb[bRowB + ni * 1024 + sck];
  };

  f32x4 acc[8][4];
#pragma unroll
  for (int i = 0; i < 8; ++i)
#pragma unroll
    for (int j = 0; j < 4; ++j)
#pragma unroll
      for (int r = 0; r < 4; ++r) acc[i][j][r] = 0.0f;

  s16x8 a0[8], b0[4], a1[8], b1[4];

  // prologue: stage tiles 0,1; wait tile 0 only (counted); preload kk0 frags
  stage(&lds[0], 0);
  stage(&lds[LDS_HALF], 1);
  asm volatile("s_waitcnt vmcnt(12)" ::: "memory");
  __builtin_amdgcn_s_barrier();
  loadFrags(a0, b0, &lds[0], 0);

  const int NT = K / BK;   // 64
  int cur = 0;
#pragma unroll 1
  for (int t = 0; t < NT; ++t) {
    ushort* ldsCur = &lds[cur * LDS_HALF];
    // issue kk1 fragment reads (drain under MFMA kk0)
    loadFrags(a1, b1, ldsCur, 1);
    if (t + 2 < NT) {
      int nx = cur + 2; if (nx >= 3) nx -= 3;
      stage(&lds[nx * LDS_HALF], t + 2);
    }
    __builtin_amdgcn_sched_barrier(0);
    // MFMA kk0 (compiler emits counted lgkm wait for a0/b0 only)
#pragma unroll
    for (int mi = 0; mi < 8; ++mi)
#pragma unroll
      for (int ni = 0; ni < 4; ++ni)
        acc[mi][ni] = __builtin_amdgcn_mfma_f32_16x16x32_bf16(
            a0[mi], b0[ni], acc[mi][ni], 0, 0, 0);
    __builtin_amdgcn_sched_barrier(0);
    if (t + 1 < NT) {
      // my t+1 staging loads landed (t+2's 12 may stay in flight)
      if (t + 2 < NT) asm volatile("s_waitcnt vmcnt(12)" ::: "memory");
      else            asm volatile("s_waitcnt vmcnt(0)" ::: "memory");
      __builtin_amdgcn_sched_barrier(0);
      __builtin_amdgcn_s_barrier();   // all waves' t+1 staging visible
      int nx1 = cur + 1; if (nx1 >= 3) nx1 -= 3;
      loadFrags(a0, b0, &lds[nx1 * LDS_HALF], 0);  // drain under MFMA kk1
      __builtin_amdgcn_sched_barrier(0);
    }
    // MFMA kk1
#pragma unroll
    for (int mi = 0; mi < 8; ++mi)
#pragma unroll
      for (int ni = 0; ni < 4; ++ni)
        acc[mi][ni] = __builtin_amdgcn_mfma_f32_16x16x32_bf16(
            a1[mi], b1[ni], acc[mi][ni], 0, 0, 0);
    __builtin_amdgcn_sched_barrier(0);
    cur += 1; if (cur == 3) cur = 0;
  }

  // epilogue: C/D layout col = lane&15, row = (lane>>4)*4 + reg
  const int ccol = lane & 15;
  const int crow = (lane >> 4) * 4;
#pragma unroll
  for (int ni = 0; ni < 4; ++ni) {
    const int gc = n0 + wid * 64 + ni * 16 + ccol;
    const float bv = HALF_N * bias[gc];
#pragma unroll
    for (int mi = 0; mi < 8; ++mi) {
      const int gr = m0 + mi * 16 + crow;
#pragma unroll
      for (int r = 0; r < 4; ++r)
        C[(size_t)(gr + r) * N + gc] = acc[mi][ni][r] + bv;
    }
  }
}

extern "C" void kernel_launch(void* const* d_in, const int* in_sizes, int n_in,
                              void* d_out, int out_size, void* d_ws, size_t ws_size,
                              hipStream_t stream) {
  const float* x = (const float*)d_in[0];
  const float* w = (const float*)d_in[1];
  const float* b = (const float*)d_in[2];
  float* y = (float*)d_out;

  const int N = in_sizes[2];             // 4096
  const int K = in_sizes[1] / N;         // 4096
  const int M = in_sizes[0] / K;         // 2048

  __hip_bfloat16* Abf = (__hip_bfloat16*)d_ws;
  __hip_bfloat16* WT  = (__hip_bfloat16*)((char*)d_ws + (size_t)M * K * 2);
  if (ws_size < (size_t)M * K * 2 + (size_t)N * K * 2) return;  // need 48 MB

  // 1) A = 3.7 * clip(x)^log2(7.4) in bf16
  const int total4 = (M * K) / 4;
  fv_kernel<<<(total4 + 255) / 256, 256, 0, stream>>>(x, Abf, total4);

  // 2) WT = transpose(w) in bf16
  wt_kernel<<<dim3(N / 64, K / 64), dim3(256), 0, stream>>>(w, WT, K, N);

  // 3) y = A @ w + 3.7*b
  const int grid = (M / BM) * (N / BN);
  gemm_kernel<<<grid, 256, 0, stream>>>(Abf, WT, b, y, M, N, K);
}

// Round 5
// 99.849 us; speedup vs baseline: 1.1566x; 1.1566x over previous
//
#include <hip/hip_runtime.h>
#include <hip/hip_bf16.h>

typedef float f32x4 __attribute__((ext_vector_type(4)));
typedef short s16x8 __attribute__((ext_vector_type(8)));

#define LOG2_N 2.887525271f   // log2(7.4)
#define HALF_N 3.7f           // n_param / 2

// ---------------- kernel 1: A[m,k] = 3.7 * clip(x,0,1)^log2(7.4)  (bf16) ----
__global__ __launch_bounds__(256) void fv_kernel(const float* __restrict__ x,
                                                 __hip_bfloat16* __restrict__ a,
                                                 int total4) {
  int i = blockIdx.x * blockDim.x + threadIdx.x;
  if (i >= total4) return;
  float4 v = reinterpret_cast<const float4*>(x)[i];
  const float* vp = reinterpret_cast<const float*>(&v);
  union { ushort4 u4; ushort s[4]; } o;
#pragma unroll
  for (int j = 0; j < 4; ++j) {
    float xc = fminf(fmaxf(vp[j], 0.0f), 1.0f);
    float r = (xc > 0.0f) ? HALF_N * exp2f(LOG2_N * __log2f(xc)) : 0.0f;
    __hip_bfloat16 h = __float2bfloat16(r);
    o.s[j] = *reinterpret_cast<ushort*>(&h);
  }
  reinterpret_cast<ushort4*>(a)[i] = o.u4;
}

// ---------------- kernel 2: WT[n][k] = bf16(w[k][n]) ------------------------
__global__ __launch_bounds__(256) void wt_kernel(const float* __restrict__ w,
                                                 __hip_bfloat16* __restrict__ wt,
                                                 int K, int N) {
  __shared__ float tile[64][65];
  const int n0 = blockIdx.x * 64;
  const int k0 = blockIdx.y * 64;
  const int tid = threadIdx.x;
#pragma unroll
  for (int i = 0; i < 16; ++i) {
    const int lin = i * 256 + tid;
    const int r = lin >> 6;   // k within tile
    const int c = lin & 63;   // n within tile
    tile[r][c] = w[(size_t)(k0 + r) * N + (n0 + c)];
  }
  __syncthreads();
  const int kk = (tid & 31) * 2;  // 0..62, even
  const int r0 = tid >> 5;        // 0..7
#pragma unroll
  for (int i = 0; i < 8; ++i) {
    const int r = r0 + i * 8;     // n within tile
    __hip_bfloat16 h0 = __float2bfloat16(tile[kk][r]);
    __hip_bfloat16 h1 = __float2bfloat16(tile[kk + 1][r]);
    ushort2 u;
    u.x = *reinterpret_cast<ushort*>(&h0);
    u.y = *reinterpret_cast<ushort*>(&h1);
    *reinterpret_cast<ushort2*>(&wt[(size_t)(n0 + r) * K + (k0 + kk)]) = u;
  }
}

// -- kernel 3: 8-wave 128x256, split-K-in-block (wave tile 128x64 over BK/2) -
#define BM 128
#define BN 256
#define BK 64
#define LDS_HALF 24576   // ushorts per buffer (48 KB): A[128][64] + B[256][64]
#define B_OFF 8192

#define GLD16(g, l)                                              \
  __builtin_amdgcn_global_load_lds(                              \
      (const __attribute__((address_space(1))) void*)(g),        \
      (__attribute__((address_space(3))) void*)(l), 16, 0, 0)

__global__ __launch_bounds__(512, 2) void gemm_kernel(
    const __hip_bfloat16* __restrict__ A,   // [M][K] bf16
    const __hip_bfloat16* __restrict__ BT,  // [N][K] bf16
    const float* __restrict__ bias,         // [N]
    float* __restrict__ C,                  // [M][N]
    int M, int N, int K) {
  __shared__ ushort lds[3 * LDS_HALF];   // 144 KB, 3-deep circular

  const int NTM = M / BM;               // 16
  const int NTN = N / BN;               // 16
  const int nwg = NTM * NTN;            // 256

  // XCD-aware bijective swizzle (nwg % 8 == 0)
  int wg = (int)blockIdx.x;
  if ((nwg & 7) == 0) wg = (wg & 7) * (nwg >> 3) + (wg >> 3);
  const int nt = wg / NTM;
  const int mt = wg % NTM;
  const int m0 = mt * BM;
  const int n0 = nt * BN;

  const int tid = threadIdx.x;
  const int lane = tid & 63;
  const int wid = tid >> 6;   // 0..7
  const int kh = wid >> 2;    // k-half of each BK tile this wave consumes
  const int wq = wid & 3;     // N quarter; wave tile = 128 x 64 over K=32

  const ushort* Au = (const ushort*)A;
  const ushort* Bu = (const ushort*)BT;

  // ---- staging (pre-swizzled global source, linear LDS dest) ----
  // LDS[row][c16] holds global[row][c16 ^ (row&7)]
  const int l8 = lane >> 3;
  const int c16s = (lane & 7) ^ l8;
  // wave stages A rows [wid*16, +16) (2 chunks) and B rows [wid*32, +32) (4)
  const ushort* aS = Au + (size_t)(m0 + wid * 16 + l8) * K + c16s * 8;
  const ushort* bS = Bu + (size_t)(n0 + wid * 32 + l8) * K + c16s * 8;
  const int aD = (wid * 16) * 64;          // ushort offsets
  const int bD = B_OFF + (wid * 32) * 64;

  auto stage0 = [&](ushort* L, int t) {    // 3 loads: 2 A-chunks + 1 B-chunk
    const size_t to = (size_t)t * BK;
    GLD16(aS + to, L + aD);
    GLD16(aS + to + (size_t)8 * K, L + aD + 512);
    GLD16(bS + to, L + bD);
  };
  auto stage1 = [&](ushort* L, int t) {    // 3 loads: remaining B-chunks
    const size_t to = (size_t)t * BK;
    GLD16(bS + to + (size_t)8 * K,  L + bD + 512);
    GLD16(bS + to + (size_t)16 * K, L + bD + 1024);
    GLD16(bS + to + (size_t)24 * K, L + bD + 1536);
  };

  // ---- fragment read addressing (swizzled ds_read); sck fixed per thread ---
  const int frow = lane & 15;
  const int lhi = lane >> 4;               // 0..3
  const int f7 = frow & 7;
  const int sck = ((kh * 4 + lhi) ^ f7) * 8;     // this wave's k-half columns
  const int aBase = frow * 64 + sck;             // a[mi] at aBase + mi*1024
  const int bBase = B_OFF + (wq * 64 + frow) * 64 + sck;  // b[ni] + ni*1024

  f32x4 acc[8][4];
#pragma unroll
  for (int i = 0; i < 8; ++i)
#pragma unroll
    for (int j = 0; j < 4; ++j)
#pragma unroll
      for (int r = 0; r < 4; ++r) acc[i][j][r] = 0.0f;

  // prologue: stage tiles 0,1; wait tile 0 only (counted)
  stage0(lds, 0);             stage1(lds, 0);
  stage0(lds + LDS_HALF, 1);  stage1(lds + LDS_HALF, 1);
  asm volatile("s_waitcnt vmcnt(6)" ::: "memory");
  __builtin_amdgcn_s_barrier();

  const int NT = K / BK;   // 64
  int cur = 0;
  for (int t = 0; t < NT; ++t) {
    ushort* ldsCur = lds + cur * LDS_HALF;
    int nx = cur + 2; if (nx >= 3) nx -= 3;
    ushort* ldsNxt = lds + nx * LDS_HALF;
    const bool pf = (t + 2 < NT);
    s16x8 a[8], b[4];
    // ---------- phase 0: frags a0..3, b0..3; stage piece 0; 16 MFMA ----------
#pragma unroll
    for (int mi = 0; mi < 4; ++mi)
      a[mi] = *(const s16x8*)&ldsCur[aBase + mi * 1024];
#pragma unroll
    for (int ni = 0; ni < 4; ++ni)
      b[ni] = *(const s16x8*)&ldsCur[bBase + ni * 1024];
    if (pf) stage0(ldsNxt, t + 2);
    __builtin_amdgcn_s_barrier();
    asm volatile("s_waitcnt lgkmcnt(0)" ::: "memory");
    __builtin_amdgcn_sched_barrier(0);
    __builtin_amdgcn_s_setprio(1);
#pragma unroll
    for (int mi = 0; mi < 4; ++mi)
#pragma unroll
      for (int ni = 0; ni < 4; ++ni)
        acc[mi][ni] = __builtin_amdgcn_mfma_f32_16x16x32_bf16(
            a[mi], b[ni], acc[mi][ni], 0, 0, 0);
    __builtin_amdgcn_s_setprio(0);
    __builtin_amdgcn_s_barrier();
    // ---------- phase 1: frags a4..7; stage piece 1; 16 MFMA -----------------
#pragma unroll
    for (int mi = 4; mi < 8; ++mi)
      a[mi] = *(const s16x8*)&ldsCur[aBase + mi * 1024];
    if (pf) stage1(ldsNxt, t + 2);
    __builtin_amdgcn_s_barrier();
    asm volatile("s_waitcnt lgkmcnt(0)" ::: "memory");
    __builtin_amdgcn_sched_barrier(0);
    __builtin_amdgcn_s_setprio(1);
#pragma unroll
    for (int mi = 4; mi < 8; ++mi)
#pragma unroll
      for (int ni = 0; ni < 4; ++ni)
        acc[mi][ni] = __builtin_amdgcn_mfma_f32_16x16x32_bf16(
            a[mi], b[ni], acc[mi][ni], 0, 0, 0);
    __builtin_amdgcn_s_setprio(0);
    if (pf)              asm volatile("s_waitcnt vmcnt(6)" ::: "memory");
    else if (t + 1 < NT) asm volatile("s_waitcnt vmcnt(0)" ::: "memory");
    __builtin_amdgcn_s_barrier();
    cur = cur + 1; if (cur == 3) cur = 0;
  }

  // ---- epilogue: cross-k-half reduction through padded LDS, then store -----
  __syncthreads();
  float* red = (float*)lds;                // 4 regions x [128][65] f32
  const int ccol = lane & 15;
  const int crow = lhi * 4;
  if (kh == 1) {
#pragma unroll
    for (int mi = 0; mi < 8; ++mi)
#pragma unroll
      for (int ni = 0; ni < 4; ++ni)
#pragma unroll
        for (int r = 0; r < 4; ++r)
          red[wq * 8320 + (mi * 16 + crow + r) * 65 + ni * 16 + ccol] =
              acc[mi][ni][r];
  }
  __syncthreads();
  if (kh == 0) {
#pragma unroll
    for (int ni = 0; ni < 4; ++ni) {
      const int gc = n0 + wq * 64 + ni * 16 + ccol;
      const float bv = HALF_N * bias[gc];
#pragma unroll
      for (int mi = 0; mi < 8; ++mi) {
        const int gr = m0 + mi * 16 + crow;
#pragma unroll
        for (int r = 0; r < 4; ++r)
          C[(size_t)(gr + r) * N + gc] =
              acc[mi][ni][r] +
              red[wq * 8320 + (mi * 16 + crow + r) * 65 + ni * 16 + ccol] + bv;
      }
    }
  }
}

extern "C" void kernel_launch(void* const* d_in, const int* in_sizes, int n_in,
                              void* d_out, int out_size, void* d_ws, size_t ws_size,
                              hipStream_t stream) {
  const float* x = (const float*)d_in[0];
  const float* w = (const float*)d_in[1];
  const float* b = (const float*)d_in[2];
  float* y = (float*)d_out;

  const int N = in_sizes[2];             // 4096
  const int K = in_sizes[1] / N;         // 4096
  const int M = in_sizes[0] / K;         // 2048

  __hip_bfloat16* Abf = (__hip_bfloat16*)d_ws;
  __hip_bfloat16* WT  = (__hip_bfloat16*)((char*)d_ws + (size_t)M * K * 2);
  if (ws_size < (size_t)M * K * 2 + (size_t)N * K * 2) return;  // need 48 MB

  // 1) A = 3.7 * clip(x)^log2(7.4) in bf16
  const int total4 = (M * K) / 4;
  fv_kernel<<<(total4 + 255) / 256, 256, 0, stream>>>(x, Abf, total4);

  // 2) WT = transpose(w) in bf16
  wt_kernel<<<dim3(N / 64, K / 64), dim3(256), 0, stream>>>(w, WT, K, N);

  // 3) y = A @ w + 3.7*b
  const int grid = (M / BM) * (N / BN);
  gemm_kernel<<<grid, 512, 0, stream>>>(Abf, WT, b, y, M, N, K);
}

// Round 6
// 94.904 us; speedup vs baseline: 1.2169x; 1.0521x over previous
//
#include <hip/hip_runtime.h>
#include <hip/hip_bf16.h>

typedef float f32x4 __attribute__((ext_vector_type(4)));
typedef short s16x8 __attribute__((ext_vector_type(8)));

#define LOG2_N 2.887525271f   // log2(7.4)
#define HALF_N 3.7f           // n_param / 2

// ---------------- kernel 1: A[m,k] = 3.7 * clip(x,0,1)^log2(7.4)  (bf16) ----
__global__ __launch_bounds__(256) void fv_kernel(const float* __restrict__ x,
                                                 __hip_bfloat16* __restrict__ a,
                                                 int total4) {
  int i = blockIdx.x * blockDim.x + threadIdx.x;
  if (i >= total4) return;
  float4 v = reinterpret_cast<const float4*>(x)[i];
  const float* vp = reinterpret_cast<const float*>(&v);
  union { ushort4 u4; ushort s[4]; } o;
#pragma unroll
  for (int j = 0; j < 4; ++j) {
    float xc = fminf(fmaxf(vp[j], 0.0f), 1.0f);
    float r = (xc > 0.0f) ? HALF_N * exp2f(LOG2_N * __log2f(xc)) : 0.0f;
    __hip_bfloat16 h = __float2bfloat16(r);
    o.s[j] = *reinterpret_cast<ushort*>(&h);
  }
  reinterpret_cast<ushort4*>(a)[i] = o.u4;
}

// ---------------- kernel 2: WT[n][k] = bf16(w[k][n]) ------------------------
__global__ __launch_bounds__(256) void wt_kernel(const float* __restrict__ w,
                                                 __hip_bfloat16* __restrict__ wt,
                                                 int K, int N) {
  __shared__ float tile[64][65];
  const int n0 = blockIdx.x * 64;
  const int k0 = blockIdx.y * 64;
  const int tid = threadIdx.x;
#pragma unroll
  for (int i = 0; i < 16; ++i) {
    const int lin = i * 256 + tid;
    const int r = lin >> 6;   // k within tile
    const int c = lin & 63;   // n within tile
    tile[r][c] = w[(size_t)(k0 + r) * N + (n0 + c)];
  }
  __syncthreads();
  const int kk = (tid & 31) * 2;  // 0..62, even
  const int r0 = tid >> 5;        // 0..7
#pragma unroll
  for (int i = 0; i < 8; ++i) {
    const int r = r0 + i * 8;     // n within tile
    __hip_bfloat16 h0 = __float2bfloat16(tile[kk][r]);
    __hip_bfloat16 h1 = __float2bfloat16(tile[kk + 1][r]);
    ushort2 u;
    u.x = *reinterpret_cast<ushort*>(&h0);
    u.y = *reinterpret_cast<ushort*>(&h1);
    *reinterpret_cast<ushort2*>(&wt[(size_t)(n0 + r) * K + (k0 + kk)]) = u;
  }
}

// -- kernel 3: 8-wave 128x256 split-K, ONE barrier/K-tile (wave-skew overlap) -
#define BM 128
#define BN 256
#define BK 64
#define LDS_HALF 24576   // ushorts per buffer (48 KB): A[128][64] + B[256][64]
#define B_OFF 8192

#define GLD16(g, l)                                              \
  __builtin_amdgcn_global_load_lds(                              \
      (const __attribute__((address_space(1))) void*)(g),        \
      (__attribute__((address_space(3))) void*)(l), 16, 0, 0)

__global__ __launch_bounds__(512, 2) void gemm_kernel(
    const __hip_bfloat16* __restrict__ A,   // [M][K] bf16
    const __hip_bfloat16* __restrict__ BT,  // [N][K] bf16
    const float* __restrict__ bias,         // [N]
    float* __restrict__ C,                  // [M][N]
    int M, int N, int K) {
  __shared__ ushort lds[3 * LDS_HALF];   // 144 KB, 3-deep circular

  const int NTM = M / BM;               // 16
  const int NTN = N / BN;               // 16
  const int nwg = NTM * NTN;            // 256

  // XCD-aware bijective swizzle (nwg % 8 == 0)
  int wg = (int)blockIdx.x;
  if ((nwg & 7) == 0) wg = (wg & 7) * (nwg >> 3) + (wg >> 3);
  const int nt = wg / NTM;
  const int mt = wg % NTM;
  const int m0 = mt * BM;
  const int n0 = nt * BN;

  const int tid = threadIdx.x;
  const int lane = tid & 63;
  const int wid = tid >> 6;   // 0..7
  const int kh = wid >> 2;    // k-half of each BK tile this wave consumes
  const int wq = wid & 3;     // N quarter; wave tile = 128 x 64 over K=32

  const ushort* Au = (const ushort*)A;
  const ushort* Bu = (const ushort*)BT;

  // ---- staging (pre-swizzled global source, linear LDS dest) ----
  // LDS[row][c16] holds global[row][c16 ^ (row&7)]
  const int l8 = lane >> 3;
  const int c16s = (lane & 7) ^ l8;
  // wave stages A rows [wid*16, +16) (2 chunks) and B rows [wid*32, +32) (4)
  const ushort* aS = Au + (size_t)(m0 + wid * 16 + l8) * K + c16s * 8;
  const ushort* bS = Bu + (size_t)(n0 + wid * 32 + l8) * K + c16s * 8;
  const int aD = (wid * 16) * 64;          // ushort offsets
  const int bD = B_OFF + (wid * 32) * 64;

  auto stage = [&](ushort* L, int t) {     // 6 gld_lds per wave = 6 KB
    const size_t to = (size_t)t * BK;
    GLD16(aS + to, L + aD);
    GLD16(aS + to + (size_t)8 * K, L + aD + 512);
    GLD16(bS + to, L + bD);
    GLD16(bS + to + (size_t)8 * K,  L + bD + 512);
    GLD16(bS + to + (size_t)16 * K, L + bD + 1024);
    GLD16(bS + to + (size_t)24 * K, L + bD + 1536);
  };

  // ---- fragment read addressing (swizzled ds_read); sck fixed per thread ---
  const int frow = lane & 15;
  const int lhi = lane >> 4;               // 0..3
  const int f7 = frow & 7;
  const int sck = ((kh * 4 + lhi) ^ f7) * 8;     // this wave's k-half columns
  const int aBase = frow * 64 + sck;             // a[mi] at aBase + mi*1024
  const int bBase = B_OFF + (wq * 64 + frow) * 64 + sck;  // b[ni] + ni*1024

  f32x4 acc[8][4];
#pragma unroll
  for (int i = 0; i < 8; ++i)
#pragma unroll
    for (int j = 0; j < 4; ++j)
#pragma unroll
      for (int r = 0; r < 4; ++r) acc[i][j][r] = 0.0f;

  // prologue: stage tiles 0,1; wait tile 0 only (counted)
  stage(lds, 0);
  stage(lds + LDS_HALF, 1);
  asm volatile("s_waitcnt vmcnt(6)" ::: "memory");
  __builtin_amdgcn_s_barrier();

  const int NT = K / BK;   // 64
  int cur = 0;
  for (int t = 0; t < NT; ++t) {
    ushort* ldsCur = lds + cur * LDS_HALF;
    int nx = cur + 2; if (nx >= 3) nx -= 3;
    const bool pf = (t + 2 < NT);
    // 12 fragment reads (compiler emits counted lgkm waits; waves skew so
    // one wave's reads drain under its SIMD-partner's MFMA cluster)
    s16x8 a[8], b[4];
#pragma unroll
    for (int mi = 0; mi < 8; ++mi)
      a[mi] = *(const s16x8*)&ldsCur[aBase + mi * 1024];
#pragma unroll
    for (int ni = 0; ni < 4; ++ni)
      b[ni] = *(const s16x8*)&ldsCur[bBase + ni * 1024];
    // prefetch t+2 into the buffer everyone finished reading last tile
    if (pf) stage(lds + nx * LDS_HALF, t + 2);
    __builtin_amdgcn_s_setprio(1);
#pragma unroll
    for (int mi = 0; mi < 8; ++mi)
#pragma unroll
      for (int ni = 0; ni < 4; ++ni)
        acc[mi][ni] = __builtin_amdgcn_mfma_f32_16x16x32_bf16(
            a[mi], b[ni], acc[mi][ni], 0, 0, 0);
    __builtin_amdgcn_s_setprio(0);
    // counted: only t+2's 6 loads may stay in flight; t+1 guaranteed landed
    if (pf)              asm volatile("s_waitcnt vmcnt(6)" ::: "memory");
    else if (t + 1 < NT) asm volatile("s_waitcnt vmcnt(0)" ::: "memory");
    __builtin_amdgcn_s_barrier();
    cur = cur + 1; if (cur == 3) cur = 0;
  }

  // ---- epilogue: cross-k-half reduction through padded LDS, then store -----
  __syncthreads();
  float* red = (float*)lds;                // 4 regions x [128][65] f32
  const int ccol = lane & 15;
  const int crow = lhi * 4;
  if (kh == 1) {
#pragma unroll
    for (int mi = 0; mi < 8; ++mi)
#pragma unroll
      for (int ni = 0; ni < 4; ++ni)
#pragma unroll
        for (int r = 0; r < 4; ++r)
          red[wq * 8320 + (mi * 16 + crow + r) * 65 + ni * 16 + ccol] =
              acc[mi][ni][r];
  }
  __syncthreads();
  if (kh == 0) {
#pragma unroll
    for (int ni = 0; ni < 4; ++ni) {
      const int gc = n0 + wq * 64 + ni * 16 + ccol;
      const float bv = HALF_N * bias[gc];
#pragma unroll
      for (int mi = 0; mi < 8; ++mi) {
        const int gr = m0 + mi * 16 + crow;
#pragma unroll
        for (int r = 0; r < 4; ++r)
          C[(size_t)(gr + r) * N + gc] =
              acc[mi][ni][r] +
              red[wq * 8320 + (mi * 16 + crow + r) * 65 + ni * 16 + ccol] + bv;
      }
    }
  }
}

extern "C" void kernel_launch(void* const* d_in, const int* in_sizes, int n_in,
                              void* d_out, int out_size, void* d_ws, size_t ws_size,
                              hipStream_t stream) {
  const float* x = (const float*)d_in[0];
  const float* w = (const float*)d_in[1];
  const float* b = (const float*)d_in[2];
  float* y = (float*)d_out;

  const int N = in_sizes[2];             // 4096
  const int K = in_sizes[1] / N;         // 4096
  const int M = in_sizes[0] / K;         // 2048

  __hip_bfloat16* Abf = (__hip_bfloat16*)d_ws;
  __hip_bfloat16* WT  = (__hip_bfloat16*)((char*)d_ws + (size_t)M * K * 2);
  if (ws_size < (size_t)M * K * 2 + (size_t)N * K * 2) return;  // need 48 MB

  // 1) A = 3.7 * clip(x)^log2(7.4) in bf16
  const int total4 = (M * K) / 4;
  fv_kernel<<<(total4 + 255) / 256, 256, 0, stream>>>(x, Abf, total4);

  // 2) WT = transpose(w) in bf16
  wt_kernel<<<dim3(N / 64, K / 64), dim3(256), 0, stream>>>(w, WT, K, N);

  // 3) y = A @ w + 3.7*b
  const int grid = (M / BM) * (N / BN);
  gemm_kernel<<<grid, 512, 0, stream>>>(Abf, WT, b, y, M, N, K);
}